// Round 12
// baseline (155.770 us; speedup 1.0000x reference)
//
#include <hip/hip_runtime.h>
#include <math.h>

#define N_NODES 50000
#define N_EDGES 800000
#define HID     128
#define N_ACT   64
#define N_GRAPH 512
#define N6      (N_NODES * 6)

// bucketing
#define NWF   2048                 // nodes per dst-window
#define LOGW  11
#define WF    25
#define CAP   40960
#define CB    16                   // feat sub-chunks per window (4 batched iters @512t)
#define DC    16                   // deg sub-chunks per window
#define EPB   2048                 // edges per place-block @512t
#define PB    ((N_EDGES + EPB - 1) / EPB)   // 391

// node stage
#define NBLK    256
#define MAXSPAN 16

// ws layout (float-sized slots)
#define F_BUCKET 0                          // WF*CAP ints
#define F_CURSOR (F_BUCKET + WF * CAP)      // 32 ints  \ memset 256B covers both
#define F_DONE   (F_CURSOR + 32)            // 32 ints  /
#define F_GSUM   (F_DONE + 32)              // N_GRAPH*HID
#define F_CNT    (F_GSUM + N_GRAPH * HID)   // N_GRAPH
#define F_DINV   (F_CNT + N_GRAPH)          // N_NODES
#define F_XSPAD  (F_DINV + N_NODES)         // N_NODES*8
#define F_DEGP   (F_XSPAD + N_NODES * 8)    // DC*N_NODES
#define F_SPART  (F_DEGP + DC * N_NODES)    // CB*N6
#define F_TOTAL  (F_SPART + CB * N6)
#define NEED_BYTES ((size_t)F_TOTAL * 4)
#define ZFLOATS (N_GRAPH * HID + N_GRAPH)   // gsum|cnt = 66048 (div 4)

// ===================== fast path =====================

// place edges into dst-window buckets; spare lanes zero gsum|cnt (consumed
// by k_node_f later). [proven rounds 10-11]
__global__ __launch_bounds__(512) void k_place(const int* __restrict__ ei,
                                               int* __restrict__ bucket,
                                               int* __restrict__ cursor,
                                               float* __restrict__ zbase) {
    __shared__ int lc[WF], lb[WF];
    int t = threadIdx.x;
    int tid = blockIdx.x * 512 + t;
    if (tid < ZFLOATS / 4) ((float4*)zbase)[tid] = make_float4(0, 0, 0, 0);

    if (t < WF) lc[t] = 0;
    __syncthreads();
    int e0 = blockIdx.x * EPB;
    int pk[4], wli[4];
#pragma unroll
    for (int i = 0; i < 4; ++i) {
        int e = e0 + i * 512 + t;
        wli[i] = -1;
        if (e < N_EDGES) {
            int src = ei[e], dst = ei[N_EDGES + e];
            int w = dst >> LOGW;
            int lp = atomicAdd(&lc[w], 1);
            pk[i] = ((dst - (w << LOGW)) << 16) | src;
            wli[i] = (w << 16) | lp;
        }
    }
    __syncthreads();
    if (t < WF) lb[t] = atomicAdd(&cursor[t], lc[t]);
    __syncthreads();
#pragma unroll
    for (int i = 0; i < 4; ++i) {
        if (wli[i] >= 0) {
            int w = wli[i] >> 16, lp = wli[i] & 0xffff;
            int pos = lb[w] + lp;
            if ((unsigned)pos < CAP) bucket[w * CAP + pos] = pk[i];
        }
    }
}

// fused degree-partials + last-block scale. Block (w,c) histograms its 1/DC
// of window w's bucket (batched 4x @512t) and writes its partial [round-6
// proven]; the 16th-arriving block of window w (one atomicAdd, NO spinning)
// reduces the 16 partials -> dinv + xs_pad for the window's 2048 nodes.
// Reduction order c=0..15 fixed -> deterministic. Writers __threadfence()
// before the done-increment so partials are at LLC; the reducer's L2 never
// cached those lines this kernel (runtime invalidates at dispatch start).
__global__ __launch_bounds__(512) void k_degscale_lb(const int* __restrict__ bucket,
                                                     const int* __restrict__ cursor,
                                                     const float* __restrict__ x,
                                                     float* __restrict__ degp,
                                                     int* __restrict__ done,
                                                     float* __restrict__ dinv,
                                                     float* __restrict__ xs_pad) {
    __shared__ float hist[NWF];
    __shared__ int isLast;
    int w = blockIdx.x, c = blockIdx.y;
    int t = threadIdx.x;
    for (int i = t; i < NWF; i += 512) hist[i] = 0.0f;
    __syncthreads();
    int cw = min(cursor[w], CAP);
    const int* bp = bucket + w * CAP;
    const int stride = DC * 512;
    int e = c * 512 + t;
    for (; e + 3 * stride < cw; e += 4 * stride) {
        int p0 = bp[e], p1 = bp[e + stride], p2 = bp[e + 2 * stride], p3 = bp[e + 3 * stride];
        atomicAdd(&hist[((unsigned)p0) >> 16], 1.0f);
        atomicAdd(&hist[((unsigned)p1) >> 16], 1.0f);
        atomicAdd(&hist[((unsigned)p2) >> 16], 1.0f);
        atomicAdd(&hist[((unsigned)p3) >> 16], 1.0f);
    }
    for (; e < cw; e += stride) atomicAdd(&hist[((unsigned)bp[e]) >> 16], 1.0f);
    __syncthreads();
    int nb = w * NWF;
    int lim = min(NWF, N_NODES - nb);
    for (int i = t; i < lim; i += 512) degp[c * N_NODES + nb + i] = hist[i];

    __threadfence();                  // each thread releases its partial stores
    __syncthreads();
    if (t == 0) isLast = (atomicAdd(&done[w], 1) == DC - 1);
    __syncthreads();
    if (!isLast) return;

    // last block of window w: reduce 16 partials -> dinv, xs_pad (2048 nodes)
#pragma unroll
    for (int j = 0; j < 2; ++j) {
        int n = nb + 2 * (t + j * 512);          // even; handles n, n+1
        if (n < N_NODES) {                        // n even < 50000 -> n+1 valid
            float d0 = 1.0f, d1 = 1.0f;           // self-loop
#pragma unroll
            for (int cc = 0; cc < DC; ++cc) {
                d0 += degp[cc * N_NODES + n];
                d1 += degp[cc * N_NODES + n + 1];
            }
            float dv0 = rsqrtf(d0), dv1 = rsqrtf(d1);
            dinv[n] = dv0; dinv[n + 1] = dv1;
            const float4* xp = (const float4*)(x + (size_t)n * 6);
            float4 xa = xp[0], xb = xp[1], xc = xp[2];
            float4* op = (float4*)(xs_pad + (size_t)n * 8);
            op[0] = make_float4(xa.x * dv0, xa.y * dv0, xa.z * dv0, xa.w * dv0);
            op[1] = make_float4(xb.x * dv0, xb.y * dv0, 0.0f, 0.0f);
            op[2] = make_float4(xb.z * dv1, xb.w * dv1, xc.x * dv1, xc.y * dv1);
            op[3] = make_float4(xc.z * dv1, xc.w * dv1, 0.0f, 0.0f);
        }
    }
}

// feature scatter: block (w,c) scans 1/CB of window w's bucket (batched 4x
// @512t, all gathers issued before atomics), LDS-accumulates, flushes.
// [proven round 6]
__global__ __launch_bounds__(512) void k_feat(const int* __restrict__ bucket,
                                              const int* __restrict__ cursor,
                                              const float* __restrict__ xs_pad,
                                              float* __restrict__ s_part) {
    __shared__ float h[NWF * 6];
    int w = blockIdx.x, c = blockIdx.y;
    int t = threadIdx.x;
    float4* h4 = (float4*)h;
    for (int i = t; i < NWF * 6 / 4; i += 512) h4[i] = make_float4(0, 0, 0, 0);
    __syncthreads();
    int cw = min(cursor[w], CAP);
    const int* bp = bucket + w * CAP;
    const int stride = CB * 512;
    int e = c * 512 + t;
    for (; e + 3 * stride < cw; e += 4 * stride) {
        int p0 = bp[e], p1 = bp[e + stride], p2 = bp[e + 2 * stride], p3 = bp[e + 3 * stride];
        const float4* q0 = (const float4*)(xs_pad + (size_t)(p0 & 0xffff) * 8);
        const float4* q1 = (const float4*)(xs_pad + (size_t)(p1 & 0xffff) * 8);
        const float4* q2 = (const float4*)(xs_pad + (size_t)(p2 & 0xffff) * 8);
        const float4* q3 = (const float4*)(xs_pad + (size_t)(p3 & 0xffff) * 8);
        float4 a0 = q0[0], b0 = q0[1];
        float4 a1 = q1[0], b1 = q1[1];
        float4 a2 = q2[0], b2 = q2[1];
        float4 a3 = q3[0], b3 = q3[1];
        float* hp;
        hp = &h[(((unsigned)p0) >> 16) * 6];
        atomicAdd(hp + 0, a0.x); atomicAdd(hp + 1, a0.y); atomicAdd(hp + 2, a0.z);
        atomicAdd(hp + 3, a0.w); atomicAdd(hp + 4, b0.x); atomicAdd(hp + 5, b0.y);
        hp = &h[(((unsigned)p1) >> 16) * 6];
        atomicAdd(hp + 0, a1.x); atomicAdd(hp + 1, a1.y); atomicAdd(hp + 2, a1.z);
        atomicAdd(hp + 3, a1.w); atomicAdd(hp + 4, b1.x); atomicAdd(hp + 5, b1.y);
        hp = &h[(((unsigned)p2) >> 16) * 6];
        atomicAdd(hp + 0, a2.x); atomicAdd(hp + 1, a2.y); atomicAdd(hp + 2, a2.z);
        atomicAdd(hp + 3, a2.w); atomicAdd(hp + 4, b2.x); atomicAdd(hp + 5, b2.y);
        hp = &h[(((unsigned)p3) >> 16) * 6];
        atomicAdd(hp + 0, a3.x); atomicAdd(hp + 1, a3.y); atomicAdd(hp + 2, a3.z);
        atomicAdd(hp + 3, a3.w); atomicAdd(hp + 4, b3.x); atomicAdd(hp + 5, b3.y);
    }
    for (; e < cw; e += stride) {
        int p = bp[e];
        const float4* q = (const float4*)(xs_pad + (size_t)(p & 0xffff) * 8);
        float4 a = q[0], b = q[1];
        float* hp = &h[(((unsigned)p) >> 16) * 6];
        atomicAdd(hp + 0, a.x); atomicAdd(hp + 1, a.y); atomicAdd(hp + 2, a.z);
        atomicAdd(hp + 3, a.w); atomicAdd(hp + 4, b.x); atomicAdd(hp + 5, b.y);
    }
    __syncthreads();
    int gb = w * NWF * 6;
    int lim = min(NWF * 6, N6 - gb);      // multiple of 4
    float4* sp4 = (float4*)(s_part + (size_t)c * N6 + gb);
    for (int i = t; i < lim / 4; i += 512) sp4[i] = h4[i];
}

// block: NBLK nodes; partial-reduce into LDS, W1+ReLU, per-graph LDS rows,
// flush interior graphs with plain stores, boundary graphs with atomics.
// [proven round 6]
__global__ __launch_bounds__(256) void k_node_f(const float* __restrict__ s_part,
                                                const float* __restrict__ xs_pad,
                                                const float* __restrict__ dinv,
                                                const int* __restrict__ batch,
                                                const float* __restrict__ w1,
                                                const float* __restrict__ b1,
                                                float* __restrict__ gsum,
                                                float* __restrict__ cnt) {
    __shared__ float sb[NBLK * 6];
    __shared__ float dvb[NBLK];
    __shared__ int   btb[NBLK];
    __shared__ float gacc[MAXSPAN][HID];
    __shared__ float gcnt[MAXSPAN];
    __shared__ int   sbnd[2];

    int nb0 = blockIdx.x * NBLK;
    int nEnd = min(nb0 + NBLK, N_NODES);
    int nCnt = nEnd - nb0;
    int lim = nCnt * 6;

    {
        float4* sb4 = (float4*)sb;
        int nv = lim >> 2;
        int g4base = (nb0 * 6) >> 2;
        for (int i = threadIdx.x; i < nv; i += 256) {
            float4 v = make_float4(0, 0, 0, 0);
#pragma unroll
            for (int c = 0; c < CB; ++c) {
                float4 p = ((const float4*)(s_part + (size_t)c * N6))[g4base + i];
                v.x += p.x; v.y += p.y; v.z += p.z; v.w += p.w;
            }
            sb4[i] = v;
        }
    }
    for (int i = threadIdx.x; i < nCnt; i += 256) {
        dvb[i] = dinv[nb0 + i];
        btb[i] = batch[nb0 + i];
    }
    if (threadIdx.x == 0) {
        sbnd[0] = (nb0 > 0) ? batch[nb0 - 1] : -1;
        sbnd[1] = (nEnd < N_NODES) ? batch[nEnd] : -1;
    }
    for (int i = threadIdx.x; i < MAXSPAN * HID; i += 256) ((float*)gacc)[i] = 0.0f;
    if (threadIdx.x < MAXSPAN) gcnt[threadIdx.x] = 0.0f;
    __syncthreads();

    for (int i = threadIdx.x; i < nCnt; i += 256) {
        const float4* xp = (const float4*)(xs_pad + (size_t)(nb0 + i) * 8);
        float4 a = xp[0], b = xp[1];
        float* sp = &sb[i * 6];
        sp[0] += a.x; sp[1] += a.y; sp[2] += a.z;
        sp[3] += a.w; sp[4] += b.x; sp[5] += b.y;
    }
    __syncthreads();

    int f = threadIdx.x & (HID - 1);
    int sub = threadIdx.x >> 7;
    float w1r[6];
#pragma unroll
    for (int k = 0; k < 6; ++k) w1r[k] = w1[k * HID + f];
    float b1f = b1[f];

    int bfirst = btb[0];
    int blast = btb[nCnt - 1];
    int span = blast - bfirst + 1;
    int bprev = sbnd[0], bnext = sbnd[1];
    int i0 = sub * (NBLK / 2);
    int i1 = min(i0 + (NBLK / 2), nCnt);

    if (span <= MAXSPAN) {
        float acc = 0.0f, rc = 0.0f;
        int curb = -1;
        for (int i = i0; i < i1; ++i) {
            const float* sp = &sb[i * 6];
            float t = 0.0f;
#pragma unroll
            for (int k = 0; k < 6; ++k) t = fmaf(sp[k], w1r[k], t);
            float a = fmaxf(fmaf(dvb[i], t, b1f), 0.0f);
            int b = btb[i];
            if (b != curb) {
                if (curb >= 0) {
                    atomicAdd(&gacc[curb - bfirst][f], acc);
                    if (f == 0) atomicAdd(&gcnt[curb - bfirst], rc);
                }
                acc = 0.0f; rc = 0.0f; curb = b;
            }
            acc += a; rc += 1.0f;
        }
        if (curb >= 0) {
            atomicAdd(&gacc[curb - bfirst][f], acc);
            if (f == 0) atomicAdd(&gcnt[curb - bfirst], rc);
        }
        __syncthreads();
        for (int idx = threadIdx.x; idx < span * HID; idx += 256) {
            int r = idx >> 7, ff = idx & (HID - 1);
            int gid = bfirst + r;
            float v = gacc[r][ff];
            if (gid == bprev || gid == bnext) atomicAdd(&gsum[gid * HID + ff], v);
            else gsum[gid * HID + ff] = v;
        }
        if (threadIdx.x < span) {
            int gid = bfirst + threadIdx.x;
            float v = gcnt[threadIdx.x];
            if (gid == bprev || gid == bnext) atomicAdd(&cnt[gid], v);
            else cnt[gid] = v;
        }
    } else {
        float acc = 0.0f, rc = 0.0f;
        int curb = -1;
        for (int i = i0; i < i1; ++i) {
            const float* sp = &sb[i * 6];
            float t = 0.0f;
#pragma unroll
            for (int k = 0; k < 6; ++k) t = fmaf(sp[k], w1r[k], t);
            float a = fmaxf(fmaf(dvb[i], t, b1f), 0.0f);
            int b = btb[i];
            if (b != curb) {
                if (curb >= 0) {
                    atomicAdd(&gsum[curb * HID + f], acc);
                    if (f == 0) atomicAdd(&cnt[curb], rc);
                }
                acc = 0.0f; rc = 0.0f; curb = b;
            }
            acc += a; rc += 1.0f;
        }
        if (curb >= 0) {
            atomicAdd(&gsum[curb * HID + f], acc);
            if (f == 0) atomicAdd(&cnt[curb], rc);
        }
    }
}

// head: 128 blocks x 4 graphs @512t [proven rounds 8-11]
__global__ __launch_bounds__(512) void k_head4(const float* __restrict__ gsum,
                                               const float* __restrict__ cnt,
                                               const float* __restrict__ wl,
                                               const float* __restrict__ bl,
                                               const float* __restrict__ w2,
                                               const float* __restrict__ b2,
                                               float* __restrict__ out) {
    __shared__ float sg[4 * HID];
    __shared__ float sg2[4 * HID];
    int t = threadIdx.x;
    int sub = t >> 7, tt = t & (HID - 1);
    int g = blockIdx.x * 4 + sub;

    float ic = 1.0f / fmaxf(cnt[g], 1.0f);
    sg[sub * HID + tt] = gsum[g * HID + tt] * ic;
    __syncthreads();

    float acc = bl[tt];
    for (int k = 0; k < HID; ++k) acc = fmaf(sg[sub * HID + k], wl[k * HID + tt], acc);
    sg2[sub * HID + tt] = fmaxf(acc, 0.0f);
    __syncthreads();

    if (tt < N_ACT) {
        float l = b2[tt];
        for (int f = 0; f < HID; ++f) l = fmaf(sg2[sub * HID + f], w2[f * N_ACT + tt], l);
        float m = l;
#pragma unroll
        for (int off = 32; off > 0; off >>= 1) m = fmaxf(m, __shfl_xor(m, off));
        float e = expf(l - m);
        float ssum = e;
#pragma unroll
        for (int off = 32; off > 0; off >>= 1) ssum += __shfl_xor(ssum, off);
        out[g * N_ACT + tt] = l - m - logf(ssum);
    }
}

// ===================== fallback path (round-1, known-correct) =====================

__global__ void k_init(float* __restrict__ deg, float* __restrict__ gsum,
                       float* __restrict__ cnt) {
    int i = blockIdx.x * blockDim.x + threadIdx.x;
    if (i < N_NODES) deg[i] = 1.0f;
    if (i < N_GRAPH * HID) gsum[i] = 0.0f;
    if (i < N_GRAPH) cnt[i] = 0.0f;
}

__global__ void k_deg(const int* __restrict__ ei, float* __restrict__ deg) {
    int e = blockIdx.x * blockDim.x + threadIdx.x;
    if (e < N_EDGES) atomicAdd(&deg[ei[N_EDGES + e]], 1.0f);
}

__global__ void k_scale(const float* __restrict__ x, const int* __restrict__ batch,
                        const float* __restrict__ deg, float* __restrict__ dinv,
                        float* __restrict__ xs, float* __restrict__ s,
                        float* __restrict__ cnt) {
    int n = blockIdx.x * blockDim.x + threadIdx.x;
    if (n >= N_NODES) return;
    float dv = rsqrtf(deg[n]);
    dinv[n] = dv;
#pragma unroll
    for (int k = 0; k < 6; ++k) {
        float v = x[n * 6 + k] * dv;
        xs[n * 6 + k] = v;
        s[n * 6 + k] = v;
    }
    atomicAdd(&cnt[batch[n]], 1.0f);
}

__global__ void k_scatter(const int* __restrict__ ei, const float* __restrict__ xs,
                          float* __restrict__ s) {
    int e = blockIdx.x * blockDim.x + threadIdx.x;
    if (e >= N_EDGES) return;
    int src = ei[e];
    int dst = ei[N_EDGES + e];
#pragma unroll
    for (int k = 0; k < 6; ++k)
        atomicAdd(&s[dst * 6 + k], xs[src * 6 + k]);
}

__global__ __launch_bounds__(256) void k_node(const float* __restrict__ s,
                                              const float* __restrict__ dinv,
                                              const int* __restrict__ batch,
                                              const float* __restrict__ w1,
                                              const float* __restrict__ b1,
                                              float* __restrict__ gsum) {
    int f = threadIdx.x & (HID - 1);
    int sub = threadIdx.x >> 7;
    int base = blockIdx.x * 16 + sub * 8;
    float w1r[6];
#pragma unroll
    for (int k = 0; k < 6; ++k) w1r[k] = w1[k * HID + f];
    float b1f = b1[f];
    float acc = 0.0f;
    int curb = -1;
    for (int i = 0; i < 8; ++i) {
        int n = base + i;
        if (n >= N_NODES) break;
        float t = 0.0f;
#pragma unroll
        for (int k = 0; k < 6; ++k) t = fmaf(s[n * 6 + k], w1r[k], t);
        float a = fmaxf(fmaf(dinv[n], t, b1f), 0.0f);
        int b = batch[n];
        if (b != curb) {
            if (curb >= 0) atomicAdd(&gsum[curb * HID + f], acc);
            acc = 0.0f;
            curb = b;
        }
        acc += a;
    }
    if (curb >= 0) atomicAdd(&gsum[curb * HID + f], acc);
}

__global__ __launch_bounds__(128) void k_head(const float* __restrict__ gsum,
                                              const float* __restrict__ cnt,
                                              const float* __restrict__ wl,
                                              const float* __restrict__ bl,
                                              const float* __restrict__ w2,
                                              const float* __restrict__ b2,
                                              float* __restrict__ out) {
    __shared__ float sg[HID];
    __shared__ float sg2[HID];
    int g = blockIdx.x;
    int t = threadIdx.x;

    float ic = 1.0f / fmaxf(cnt[g], 1.0f);
    sg[t] = gsum[g * HID + t] * ic;
    __syncthreads();

    float acc = bl[t];
    for (int k = 0; k < HID; ++k) acc = fmaf(sg[k], wl[k * HID + t], acc);
    sg2[t] = fmaxf(acc, 0.0f);
    __syncthreads();

    if (t < N_ACT) {
        float l = b2[t];
        for (int f = 0; f < HID; ++f) l = fmaf(sg2[f], w2[f * N_ACT + t], l);
        float m = l;
#pragma unroll
        for (int off = 32; off > 0; off >>= 1) m = fmaxf(m, __shfl_xor(m, off));
        float e = expf(l - m);
        float ssum = e;
#pragma unroll
        for (int off = 32; off > 0; off >>= 1) ssum += __shfl_xor(ssum, off);
        out[g * N_ACT + t] = l - m - logf(ssum);
    }
}

// ===================== launch =====================

extern "C" void kernel_launch(void* const* d_in, const int* in_sizes, int n_in,
                              void* d_out, int out_size, void* d_ws, size_t ws_size,
                              hipStream_t stream) {
    const float* x     = (const float*)d_in[0];
    const int*   ei    = (const int*)d_in[1];
    const int*   batch = (const int*)d_in[2];
    const float* w1    = (const float*)d_in[3];
    const float* b1    = (const float*)d_in[4];
    const float* wl    = (const float*)d_in[5];
    const float* bl    = (const float*)d_in[6];
    const float* w2    = (const float*)d_in[7];
    const float* b2    = (const float*)d_in[8];
    float* out = (float*)d_out;
    float* ws = (float*)d_ws;

    if (ws_size >= NEED_BYTES) {
        int*   bucket = (int*)(ws + F_BUCKET);
        int*   cursor = (int*)(ws + F_CURSOR);
        int*   done   = (int*)(ws + F_DONE);
        float* gsum   = ws + F_GSUM;
        float* cnt    = ws + F_CNT;
        float* dinv   = ws + F_DINV;
        float* xs_pad = ws + F_XSPAD;
        float* degp   = ws + F_DEGP;
        float* s_part = ws + F_SPART;

        hipMemsetAsync(cursor, 0, 64 * sizeof(int), stream);   // cursor|done
        k_place<<<PB, 512, 0, stream>>>(ei, bucket, cursor, gsum);
        k_degscale_lb<<<dim3(WF, DC), 512, 0, stream>>>(bucket, cursor, x, degp, done, dinv, xs_pad);
        k_feat<<<dim3(WF, CB), 512, 0, stream>>>(bucket, cursor, xs_pad, s_part);
        k_node_f<<<(N_NODES + NBLK - 1) / NBLK, 256, 0, stream>>>(s_part, xs_pad, dinv, batch, w1, b1, gsum, cnt);
        k_head4<<<N_GRAPH / 4, 512, 0, stream>>>(gsum, cnt, wl, bl, w2, b2, out);
    } else {
        float* deg  = ws;
        float* dinv = deg + N_NODES;
        float* xs   = dinv + N_NODES;
        float* s    = xs + N6;
        float* gsum = s + N6;
        float* cnt  = gsum + N_GRAPH * HID;

        k_init<<<(N_GRAPH * HID + 255) / 256, 256, 0, stream>>>(deg, gsum, cnt);
        k_deg<<<(N_EDGES + 255) / 256, 256, 0, stream>>>(ei, deg);
        k_scale<<<(N_NODES + 255) / 256, 256, 0, stream>>>(x, batch, deg, dinv, xs, s, cnt);
        k_scatter<<<(N_EDGES + 255) / 256, 256, 0, stream>>>(ei, xs, s);
        k_node<<<(N_NODES + 15) / 16, 256, 0, stream>>>(s, dinv, batch, w1, b1, gsum);
        k_head<<<N_GRAPH, 128, 0, stream>>>(gsum, cnt, wl, bl, w2, b2, out);
    }
}

// Round 13
// 89.464 us; speedup vs baseline: 1.7411x; 1.7411x over previous
//
#include <hip/hip_runtime.h>
#include <math.h>

#define N_NODES 50000
#define N_EDGES 800000
#define HID     128
#define N_ACT   64
#define N_GRAPH 512
#define N6      (N_NODES * 6)

// bucketing
#define NWF   2048                 // nodes per dst-window
#define LOGW  11
#define WF    25
#define CAP   40960
#define CB    16                   // feat sub-chunks per window (4 batched iters @512t)
#define DC    16                   // deg sub-chunks per window
#define EPB   2048                 // edges per place-block @512t
#define PB    ((N_EDGES + EPB - 1) / EPB)   // 391

// nodehead stage
#define MAXN  768                  // max nodes per 4-graph block chunk (mean 390, +18 sigma)

// ws layout (float-sized slots)
#define F_BUCKET 0                          // WF*CAP ints
#define F_CURSOR (F_BUCKET + WF * CAP)      // 32 ints (memset 128B)
#define F_GSTART (F_CURSOR + 32)            // 516 ints (513 used; written fully each call)
#define F_DINV   (F_GSTART + 516)           // N_NODES
#define F_XSPAD  (F_DINV + N_NODES)         // N_NODES*8
#define F_DEGP   (F_XSPAD + N_NODES * 8)    // DC*N_NODES
#define F_SPART  (F_DEGP + DC * N_NODES)    // CB*N6
#define F_TOTAL  (F_SPART + CB * N6)
#define NEED_BYTES ((size_t)F_TOTAL * 4)

// ===================== fast path =====================

// place edges into dst-window buckets. [proven rounds 10-12; gsum-zeroing removed]
__global__ __launch_bounds__(512) void k_place(const int* __restrict__ ei,
                                               int* __restrict__ bucket,
                                               int* __restrict__ cursor) {
    __shared__ int lc[WF], lb[WF];
    int t = threadIdx.x;
    if (t < WF) lc[t] = 0;
    __syncthreads();
    int e0 = blockIdx.x * EPB;
    int pk[4], wli[4];
#pragma unroll
    for (int i = 0; i < 4; ++i) {
        int e = e0 + i * 512 + t;
        wli[i] = -1;
        if (e < N_EDGES) {
            int src = ei[e], dst = ei[N_EDGES + e];
            int w = dst >> LOGW;
            int lp = atomicAdd(&lc[w], 1);
            pk[i] = ((dst - (w << LOGW)) << 16) | src;
            wli[i] = (w << 16) | lp;
        }
    }
    __syncthreads();
    if (t < WF) lb[t] = atomicAdd(&cursor[t], lc[t]);
    __syncthreads();
#pragma unroll
    for (int i = 0; i < 4; ++i) {
        if (wli[i] >= 0) {
            int w = wli[i] >> 16, lp = wli[i] & 0xffff;
            int pos = lb[w] + lp;
            if ((unsigned)pos < CAP) bucket[w * CAP + pos] = pk[i];
        }
    }
}

// degree partials: block (w,c) scans 1/DC of window w's bucket (batched 4x
// @512t), histograms the full 2048-node window in LDS, writes partial.
// [proven rounds 6/11]
__global__ __launch_bounds__(512) void k_degp(const int* __restrict__ bucket,
                                              const int* __restrict__ cursor,
                                              float* __restrict__ degp) {
    __shared__ float hist[NWF];
    int w = blockIdx.x, c = blockIdx.y;
    int t = threadIdx.x;
    for (int i = t; i < NWF; i += 512) hist[i] = 0.0f;
    __syncthreads();
    int cw = min(cursor[w], CAP);
    const int* bp = bucket + w * CAP;
    const int stride = DC * 512;
    int e = c * 512 + t;
    for (; e + 3 * stride < cw; e += 4 * stride) {
        int p0 = bp[e], p1 = bp[e + stride], p2 = bp[e + 2 * stride], p3 = bp[e + 3 * stride];
        atomicAdd(&hist[((unsigned)p0) >> 16], 1.0f);
        atomicAdd(&hist[((unsigned)p1) >> 16], 1.0f);
        atomicAdd(&hist[((unsigned)p2) >> 16], 1.0f);
        atomicAdd(&hist[((unsigned)p3) >> 16], 1.0f);
    }
    for (; e < cw; e += stride) atomicAdd(&hist[((unsigned)bp[e]) >> 16], 1.0f);
    __syncthreads();
    int nb = w * NWF;
    int lim = min(NWF, N_NODES - nb);
    for (int i = t; i < lim; i += 512) degp[c * N_NODES + nb + i] = hist[i];
}

// mark graph-start boundaries for node m (batch sorted; covers all g in 0..512)
__device__ __forceinline__ void mark_gstart(const int* __restrict__ batch, int m,
                                            int* __restrict__ gstart) {
    int bm = batch[m];
    if (m == 0) {
        for (int g = 0; g <= bm; ++g) gstart[g] = 0;
    } else {
        int bp = batch[m - 1];
        for (int g = bp + 1; g <= bm; ++g) gstart[g] = m;
    }
    if (m == N_NODES - 1) {
        for (int g = bm + 1; g <= N_GRAPH; ++g) gstart[g] = N_NODES;
    }
}

// reduce DC degree partials -> dinv, xs_pad (2 nodes/thread) + gstart marking.
// [proven round 6/11; gstart addition is independent per-thread work]
__global__ __launch_bounds__(256) void k_scale2(const float* __restrict__ degp,
                                                const float* __restrict__ x,
                                                const int* __restrict__ batch,
                                                float* __restrict__ dinv,
                                                float* __restrict__ xs_pad,
                                                int* __restrict__ gstart) {
    int n = blockIdx.x * 512 + 2 * threadIdx.x;
    if (n >= N_NODES) return;                 // N_NODES even -> n+1 also valid
    float d0 = 1.0f, d1 = 1.0f;               // self-loop
#pragma unroll
    for (int c = 0; c < DC; ++c) {
        d0 += degp[c * N_NODES + n];
        d1 += degp[c * N_NODES + n + 1];
    }
    float dv0 = rsqrtf(d0), dv1 = rsqrtf(d1);
    dinv[n] = dv0; dinv[n + 1] = dv1;
    const float4* xp = (const float4*)(x + (size_t)n * 6);
    float4 xa = xp[0], xb = xp[1], xc = xp[2];
    float4* op = (float4*)(xs_pad + (size_t)n * 8);
    op[0] = make_float4(xa.x * dv0, xa.y * dv0, xa.z * dv0, xa.w * dv0);
    op[1] = make_float4(xb.x * dv0, xb.y * dv0, 0.0f, 0.0f);
    op[2] = make_float4(xb.z * dv1, xb.w * dv1, xc.x * dv1, xc.y * dv1);
    op[3] = make_float4(xc.z * dv1, xc.w * dv1, 0.0f, 0.0f);
    mark_gstart(batch, n, gstart);
    mark_gstart(batch, n + 1, gstart);
}

// feature scatter: block (w,c) scans 1/CB of window w's bucket (batched 4x
// @512t, all gathers issued before atomics), LDS-accumulates, flushes.
// [proven rounds 6/11]
__global__ __launch_bounds__(512) void k_feat(const int* __restrict__ bucket,
                                              const int* __restrict__ cursor,
                                              const float* __restrict__ xs_pad,
                                              float* __restrict__ s_part) {
    __shared__ float h[NWF * 6];
    int w = blockIdx.x, c = blockIdx.y;
    int t = threadIdx.x;
    float4* h4 = (float4*)h;
    for (int i = t; i < NWF * 6 / 4; i += 512) h4[i] = make_float4(0, 0, 0, 0);
    __syncthreads();
    int cw = min(cursor[w], CAP);
    const int* bp = bucket + w * CAP;
    const int stride = CB * 512;
    int e = c * 512 + t;
    for (; e + 3 * stride < cw; e += 4 * stride) {
        int p0 = bp[e], p1 = bp[e + stride], p2 = bp[e + 2 * stride], p3 = bp[e + 3 * stride];
        const float4* q0 = (const float4*)(xs_pad + (size_t)(p0 & 0xffff) * 8);
        const float4* q1 = (const float4*)(xs_pad + (size_t)(p1 & 0xffff) * 8);
        const float4* q2 = (const float4*)(xs_pad + (size_t)(p2 & 0xffff) * 8);
        const float4* q3 = (const float4*)(xs_pad + (size_t)(p3 & 0xffff) * 8);
        float4 a0 = q0[0], b0 = q0[1];
        float4 a1 = q1[0], b1 = q1[1];
        float4 a2 = q2[0], b2 = q2[1];
        float4 a3 = q3[0], b3 = q3[1];
        float* hp;
        hp = &h[(((unsigned)p0) >> 16) * 6];
        atomicAdd(hp + 0, a0.x); atomicAdd(hp + 1, a0.y); atomicAdd(hp + 2, a0.z);
        atomicAdd(hp + 3, a0.w); atomicAdd(hp + 4, b0.x); atomicAdd(hp + 5, b0.y);
        hp = &h[(((unsigned)p1) >> 16) * 6];
        atomicAdd(hp + 0, a1.x); atomicAdd(hp + 1, a1.y); atomicAdd(hp + 2, a1.z);
        atomicAdd(hp + 3, a1.w); atomicAdd(hp + 4, b1.x); atomicAdd(hp + 5, b1.y);
        hp = &h[(((unsigned)p2) >> 16) * 6];
        atomicAdd(hp + 0, a2.x); atomicAdd(hp + 1, a2.y); atomicAdd(hp + 2, a2.z);
        atomicAdd(hp + 3, a2.w); atomicAdd(hp + 4, b2.x); atomicAdd(hp + 5, b2.y);
        hp = &h[(((unsigned)p3) >> 16) * 6];
        atomicAdd(hp + 0, a3.x); atomicAdd(hp + 1, a3.y); atomicAdd(hp + 2, a3.z);
        atomicAdd(hp + 3, a3.w); atomicAdd(hp + 4, b3.x); atomicAdd(hp + 5, b3.y);
    }
    for (; e < cw; e += stride) {
        int p = bp[e];
        const float4* q = (const float4*)(xs_pad + (size_t)(p & 0xffff) * 8);
        float4 a = q[0], b = q[1];
        float* hp = &h[(((unsigned)p) >> 16) * 6];
        atomicAdd(hp + 0, a.x); atomicAdd(hp + 1, a.y); atomicAdd(hp + 2, a.z);
        atomicAdd(hp + 3, a.w); atomicAdd(hp + 4, b.x); atomicAdd(hp + 5, b.y);
    }
    __syncthreads();
    int gb = w * NWF * 6;
    int lim = min(NWF * 6, N6 - gb);      // multiple of 4
    float4* sp4 = (float4*)(s_part + (size_t)c * N6 + gb);
    for (int i = t; i < lim / 4; i += 512) sp4[i] = h4[i];
}

// fused node+head: block owns 4 whole graphs (graphs never split -> no
// atomics, fixed order -> deterministic). Reduce s_part+self-loop for the
// block's node range into LDS (chunked at MAXN), W1+ReLU, per-graph mean,
// then MLP + log_softmax (structure proven rounds 8-12 as k_head4).
__global__ __launch_bounds__(512) void k_nodehead(const float* __restrict__ s_part,
                                                  const float* __restrict__ xs_pad,
                                                  const float* __restrict__ dinv,
                                                  const int* __restrict__ gstart,
                                                  const float* __restrict__ w1,
                                                  const float* __restrict__ b1,
                                                  const float* __restrict__ wl,
                                                  const float* __restrict__ bl,
                                                  const float* __restrict__ w2,
                                                  const float* __restrict__ b2,
                                                  float* __restrict__ out) {
    __shared__ float sb[MAXN * 6];
    __shared__ float dvb[MAXN];
    __shared__ float sg[4 * HID];
    __shared__ float sg2[4 * HID];
    __shared__ int gb[5];
    int t = threadIdx.x;
    int g0 = blockIdx.x * 4;
    if (t < 5) gb[t] = gstart[g0 + t];
    __syncthreads();
    int ns = gb[0], ne = gb[4];
    int sub = t >> 7, f = t & (HID - 1);
    float w1r[6];
#pragma unroll
    for (int k = 0; k < 6; ++k) w1r[k] = w1[k * HID + f];
    float b1f = b1[f];
    float acc = 0.0f;

    for (int base = ns; base < ne; base += MAXN) {
        int cc = min(MAXN, ne - base);
        __syncthreads();                       // protect sb/dvb reuse across chunks
        // phase A: reduce CB s_part partials (float2: base*6 is 2-aligned)
        {
            float2* sb2 = (float2*)sb;
            int nel = cc * 3;
            int g2 = base * 3;
            for (int i = t; i < nel; i += 512) {
                float2 v = make_float2(0.0f, 0.0f);
#pragma unroll
                for (int c = 0; c < CB; ++c) {
                    float2 p = ((const float2*)(s_part + (size_t)c * N6))[g2 + i];
                    v.x += p.x; v.y += p.y;
                }
                sb2[i] = v;
            }
        }
        // phase B: add self-loop term; stage dinv
        for (int i = t; i < cc; i += 512) {
            int n = base + i;
            const float4* xp = (const float4*)(xs_pad + (size_t)n * 8);
            float4 a = xp[0], bq = xp[1];
            float* sp = &sb[i * 6];
            sp[0] += a.x; sp[1] += a.y; sp[2] += a.z;
            sp[3] += a.w; sp[4] += bq.x; sp[5] += bq.y;
            dvb[i] = dinv[n];
        }
        __syncthreads();
        // phase C: W1 + ReLU + accumulate (thread = (graph sub, feature f))
        int lo = max(gb[sub], base);
        int hi = min(gb[sub + 1], base + cc);
        for (int n = lo; n < hi; ++n) {
            int i = n - base;
            const float* sp = &sb[i * 6];
            float tv = 0.0f;
#pragma unroll
            for (int k = 0; k < 6; ++k) tv = fmaf(sp[k], w1r[k], tv);
            acc += fmaxf(fmaf(dvb[i], tv, b1f), 0.0f);
        }
    }

    // per-graph mean
    int cnt = gb[sub + 1] - gb[sub];
    float ic = 1.0f / fmaxf((float)cnt, 1.0f);
    sg[sub * HID + f] = acc * ic;
    __syncthreads();

    // head MLP + log_softmax
    float a2 = bl[f];
    for (int k = 0; k < HID; ++k) a2 = fmaf(sg[sub * HID + k], wl[k * HID + f], a2);
    sg2[sub * HID + f] = fmaxf(a2, 0.0f);
    __syncthreads();

    if (f < N_ACT) {                           // t = sub*128 + 0..63 = full wave
        float l = b2[f];
        for (int ff = 0; ff < HID; ++ff) l = fmaf(sg2[sub * HID + ff], w2[ff * N_ACT + f], l);
        float m = l;
#pragma unroll
        for (int off = 32; off > 0; off >>= 1) m = fmaxf(m, __shfl_xor(m, off));
        float e = expf(l - m);
        float ssum = e;
#pragma unroll
        for (int off = 32; off > 0; off >>= 1) ssum += __shfl_xor(ssum, off);
        out[(g0 + sub) * N_ACT + f] = l - m - logf(ssum);
    }
}

// ===================== fallback path (round-1, known-correct) =====================

__global__ void k_init(float* __restrict__ deg, float* __restrict__ gsum,
                       float* __restrict__ cnt) {
    int i = blockIdx.x * blockDim.x + threadIdx.x;
    if (i < N_NODES) deg[i] = 1.0f;
    if (i < N_GRAPH * HID) gsum[i] = 0.0f;
    if (i < N_GRAPH) cnt[i] = 0.0f;
}

__global__ void k_deg(const int* __restrict__ ei, float* __restrict__ deg) {
    int e = blockIdx.x * blockDim.x + threadIdx.x;
    if (e < N_EDGES) atomicAdd(&deg[ei[N_EDGES + e]], 1.0f);
}

__global__ void k_scale(const float* __restrict__ x, const int* __restrict__ batch,
                        const float* __restrict__ deg, float* __restrict__ dinv,
                        float* __restrict__ xs, float* __restrict__ s,
                        float* __restrict__ cnt) {
    int n = blockIdx.x * blockDim.x + threadIdx.x;
    if (n >= N_NODES) return;
    float dv = rsqrtf(deg[n]);
    dinv[n] = dv;
#pragma unroll
    for (int k = 0; k < 6; ++k) {
        float v = x[n * 6 + k] * dv;
        xs[n * 6 + k] = v;
        s[n * 6 + k] = v;
    }
    atomicAdd(&cnt[batch[n]], 1.0f);
}

__global__ void k_scatter(const int* __restrict__ ei, const float* __restrict__ xs,
                          float* __restrict__ s) {
    int e = blockIdx.x * blockDim.x + threadIdx.x;
    if (e >= N_EDGES) return;
    int src = ei[e];
    int dst = ei[N_EDGES + e];
#pragma unroll
    for (int k = 0; k < 6; ++k)
        atomicAdd(&s[dst * 6 + k], xs[src * 6 + k]);
}

__global__ __launch_bounds__(256) void k_node(const float* __restrict__ s,
                                              const float* __restrict__ dinv,
                                              const int* __restrict__ batch,
                                              const float* __restrict__ w1,
                                              const float* __restrict__ b1,
                                              float* __restrict__ gsum) {
    int f = threadIdx.x & (HID - 1);
    int sub = threadIdx.x >> 7;
    int base = blockIdx.x * 16 + sub * 8;
    float w1r[6];
#pragma unroll
    for (int k = 0; k < 6; ++k) w1r[k] = w1[k * HID + f];
    float b1f = b1[f];
    float acc = 0.0f;
    int curb = -1;
    for (int i = 0; i < 8; ++i) {
        int n = base + i;
        if (n >= N_NODES) break;
        float t = 0.0f;
#pragma unroll
        for (int k = 0; k < 6; ++k) t = fmaf(s[n * 6 + k], w1r[k], t);
        float a = fmaxf(fmaf(dinv[n], t, b1f), 0.0f);
        int b = batch[n];
        if (b != curb) {
            if (curb >= 0) atomicAdd(&gsum[curb * HID + f], acc);
            acc = 0.0f;
            curb = b;
        }
        acc += a;
    }
    if (curb >= 0) atomicAdd(&gsum[curb * HID + f], acc);
}

__global__ __launch_bounds__(128) void k_head(const float* __restrict__ gsum,
                                              const float* __restrict__ cnt,
                                              const float* __restrict__ wl,
                                              const float* __restrict__ bl,
                                              const float* __restrict__ w2,
                                              const float* __restrict__ b2,
                                              float* __restrict__ out) {
    __shared__ float sg[HID];
    __shared__ float sg2[HID];
    int g = blockIdx.x;
    int t = threadIdx.x;

    float ic = 1.0f / fmaxf(cnt[g], 1.0f);
    sg[t] = gsum[g * HID + t] * ic;
    __syncthreads();

    float acc = bl[t];
    for (int k = 0; k < HID; ++k) acc = fmaf(sg[k], wl[k * HID + t], acc);
    sg2[t] = fmaxf(acc, 0.0f);
    __syncthreads();

    if (t < N_ACT) {
        float l = b2[t];
        for (int f = 0; f < HID; ++f) l = fmaf(sg2[f], w2[f * N_ACT + t], l);
        float m = l;
#pragma unroll
        for (int off = 32; off > 0; off >>= 1) m = fmaxf(m, __shfl_xor(m, off));
        float e = expf(l - m);
        float ssum = e;
#pragma unroll
        for (int off = 32; off > 0; off >>= 1) ssum += __shfl_xor(ssum, off);
        out[g * N_ACT + t] = l - m - logf(ssum);
    }
}

// ===================== launch =====================

extern "C" void kernel_launch(void* const* d_in, const int* in_sizes, int n_in,
                              void* d_out, int out_size, void* d_ws, size_t ws_size,
                              hipStream_t stream) {
    const float* x     = (const float*)d_in[0];
    const int*   ei    = (const int*)d_in[1];
    const int*   batch = (const int*)d_in[2];
    const float* w1    = (const float*)d_in[3];
    const float* b1    = (const float*)d_in[4];
    const float* wl    = (const float*)d_in[5];
    const float* bl    = (const float*)d_in[6];
    const float* w2    = (const float*)d_in[7];
    const float* b2    = (const float*)d_in[8];
    float* out = (float*)d_out;
    float* ws = (float*)d_ws;

    if (ws_size >= NEED_BYTES) {
        int*   bucket = (int*)(ws + F_BUCKET);
        int*   cursor = (int*)(ws + F_CURSOR);
        int*   gstart = (int*)(ws + F_GSTART);
        float* dinv   = ws + F_DINV;
        float* xs_pad = ws + F_XSPAD;
        float* degp   = ws + F_DEGP;
        float* s_part = ws + F_SPART;

        hipMemsetAsync(cursor, 0, 32 * sizeof(int), stream);
        k_place<<<PB, 512, 0, stream>>>(ei, bucket, cursor);
        k_degp<<<dim3(WF, DC), 512, 0, stream>>>(bucket, cursor, degp);
        k_scale2<<<(N_NODES + 511) / 512, 256, 0, stream>>>(degp, x, batch, dinv, xs_pad, gstart);
        k_feat<<<dim3(WF, CB), 512, 0, stream>>>(bucket, cursor, xs_pad, s_part);
        k_nodehead<<<N_GRAPH / 4, 512, 0, stream>>>(s_part, xs_pad, dinv, gstart,
                                                    w1, b1, wl, bl, w2, b2, out);
    } else {
        float* deg  = ws;
        float* dinv = deg + N_NODES;
        float* xs   = dinv + N_NODES;
        float* s    = xs + N6;
        float* gsum = s + N6;
        float* cnt  = gsum + N_GRAPH * HID;

        k_init<<<(N_GRAPH * HID + 255) / 256, 256, 0, stream>>>(deg, gsum, cnt);
        k_deg<<<(N_EDGES + 255) / 256, 256, 0, stream>>>(ei, deg);
        k_scale<<<(N_NODES + 255) / 256, 256, 0, stream>>>(x, batch, deg, dinv, xs, s, cnt);
        k_scatter<<<(N_EDGES + 255) / 256, 256, 0, stream>>>(ei, xs, s);
        k_node<<<(N_NODES + 15) / 16, 256, 0, stream>>>(s, dinv, batch, w1, b1, gsum);
        k_head<<<N_GRAPH, 128, 0, stream>>>(gsum, cnt, wl, bl, w2, b2, out);
    }
}

// Round 14
// 82.840 us; speedup vs baseline: 1.8804x; 1.0800x over previous
//
#include <hip/hip_runtime.h>
#include <math.h>

#define N_NODES 50000
#define N_EDGES 800000
#define HID     128
#define N_ACT   64
#define N_GRAPH 512
#define N6      (N_NODES * 6)

// bucketing (deterministic segmented: no global cursor, no memset)
#define NWF    2048                // nodes per dst-window
#define LOGW   11
#define WF     25
#define CB     16                  // feat sub-chunks per window
#define DC     16                  // deg sub-chunks per window
#define EPB    2048                // edges per place-block @512t
#define PB     ((N_EDGES + EPB - 1) / EPB)   // 391
#define SEGCAP 160                 // per-(block,window) segment capacity (mean 82, +8.8 sigma)

// nodehead stage
#define MAXN  768                  // max nodes per 4-graph block chunk (mean 390, +18 sigma)

// ws layout (float-sized slots)
#define F_BUCKET 0                                  // WF*PB*SEGCAP ints
#define F_COUNTS (F_BUCKET + WF * PB * SEGCAP)      // WF*PB ints (padded to 9776)
#define F_GSTART (F_COUNTS + 9776)                  // 516 ints (513 used; fully rewritten)
#define F_DINV   (F_GSTART + 516)                   // N_NODES
#define F_XSPAD  (F_DINV + N_NODES)                 // N_NODES*8 (float4-aligned)
#define F_DEGP   (F_XSPAD + N_NODES * 8)            // DC*N_NODES
#define F_SPART  (F_DEGP + DC * N_NODES)            // CB*N6
#define F_TOTAL  (F_SPART + CB * N6)
#define NEED_BYTES ((size_t)F_TOTAL * 4)

// ===================== fast path =====================

// place edges into fixed per-(block,window) segments. No global atomics, no
// cursor: the LDS slot index IS the final slot. counts[] fully rewritten
// every call (poison-safe). [derived from rounds 10-13 proven k_place]
__global__ __launch_bounds__(512) void k_place(const int* __restrict__ ei,
                                               int* __restrict__ bucket,
                                               int* __restrict__ counts) {
    __shared__ int lc[WF];
    int t = threadIdx.x;
    int b = blockIdx.x;
    if (t < WF) lc[t] = 0;
    __syncthreads();
    int e0 = b * EPB;
    int pk[4], wli[4];
#pragma unroll
    for (int i = 0; i < 4; ++i) {
        int e = e0 + i * 512 + t;
        wli[i] = -1;
        if (e < N_EDGES) {
            int src = ei[e], dst = ei[N_EDGES + e];
            int w = dst >> LOGW;
            int lp = atomicAdd(&lc[w], 1);            // slot within (block,window) segment
            pk[i] = ((dst - (w << LOGW)) << 16) | src;
            wli[i] = (w << 16) | lp;
        }
    }
    __syncthreads();
    if (t < WF) counts[t * PB + b] = min(lc[t], SEGCAP);
#pragma unroll
    for (int i = 0; i < 4; ++i) {
        if (wli[i] >= 0) {
            int w = wli[i] >> 16, lp = wli[i] & 0xffff;
            if (lp < SEGCAP) bucket[(w * PB + b) * SEGCAP + lp] = pk[i];
        }
    }
}

// degree partials over segmented bucket: block (w,c) scans segments
// b ≡ c (mod DC) with count-masked slots (batched 4x @512t), histograms the
// full window in LDS, writes partial. [scan structure from proven round-6 k_degp]
__global__ __launch_bounds__(512) void k_degp(const int* __restrict__ bucket,
                                              const int* __restrict__ counts,
                                              float* __restrict__ degp) {
    __shared__ float hist[NWF];
    __shared__ int scnt[32];
    int w = blockIdx.x, c = blockIdx.y;
    int t = threadIdx.x;
    int nseg = (PB - 1 - c) / DC + 1;                 // 25 for c<=6 else 24
    for (int i = t; i < NWF; i += 512) hist[i] = 0.0f;
    if (t < nseg) scnt[t] = counts[w * PB + c + DC * t];
    __syncthreads();
    int total = nseg * SEGCAP;
    int base = (w * PB + c) * SEGCAP;
    int s = t;
    for (; s + 3 * 512 < total; s += 4 * 512) {
        int s0 = s, s1 = s + 512, s2 = s + 1024, s3 = s + 1536;
        int j0 = s0 / SEGCAP, j1 = s1 / SEGCAP, j2 = s2 / SEGCAP, j3 = s3 / SEGCAP;
        int e0 = s0 - j0 * SEGCAP, e1 = s1 - j1 * SEGCAP, e2 = s2 - j2 * SEGCAP, e3 = s3 - j3 * SEGCAP;
        bool v0 = e0 < scnt[j0], v1 = e1 < scnt[j1], v2 = e2 < scnt[j2], v3 = e3 < scnt[j3];
        int p0 = 0, p1 = 0, p2 = 0, p3 = 0;
        if (v0) p0 = bucket[base + j0 * (DC * SEGCAP) + e0];
        if (v1) p1 = bucket[base + j1 * (DC * SEGCAP) + e1];
        if (v2) p2 = bucket[base + j2 * (DC * SEGCAP) + e2];
        if (v3) p3 = bucket[base + j3 * (DC * SEGCAP) + e3];
        if (v0) atomicAdd(&hist[((unsigned)p0) >> 16], 1.0f);
        if (v1) atomicAdd(&hist[((unsigned)p1) >> 16], 1.0f);
        if (v2) atomicAdd(&hist[((unsigned)p2) >> 16], 1.0f);
        if (v3) atomicAdd(&hist[((unsigned)p3) >> 16], 1.0f);
    }
    for (; s < total; s += 512) {
        int j = s / SEGCAP, e = s - j * SEGCAP;
        if (e < scnt[j]) {
            int p = bucket[base + j * (DC * SEGCAP) + e];
            atomicAdd(&hist[((unsigned)p) >> 16], 1.0f);
        }
    }
    __syncthreads();
    int nb = w * NWF;
    int lim = min(NWF, N_NODES - nb);
    for (int i = t; i < lim; i += 512) degp[c * N_NODES + nb + i] = hist[i];
}

// mark graph-start boundaries for node m (batch sorted; covers all g in 0..512)
__device__ __forceinline__ void mark_gstart(const int* __restrict__ batch, int m,
                                            int* __restrict__ gstart) {
    int bm = batch[m];
    if (m == 0) {
        for (int g = 0; g <= bm; ++g) gstart[g] = 0;
    } else {
        int bp = batch[m - 1];
        for (int g = bp + 1; g <= bm; ++g) gstart[g] = m;
    }
    if (m == N_NODES - 1) {
        for (int g = bm + 1; g <= N_GRAPH; ++g) gstart[g] = N_NODES;
    }
}

// reduce DC degree partials -> dinv, xs_pad (2 nodes/thread) + gstart marking.
// [proven rounds 6/11/13]
__global__ __launch_bounds__(256) void k_scale2(const float* __restrict__ degp,
                                                const float* __restrict__ x,
                                                const int* __restrict__ batch,
                                                float* __restrict__ dinv,
                                                float* __restrict__ xs_pad,
                                                int* __restrict__ gstart) {
    int n = blockIdx.x * 512 + 2 * threadIdx.x;
    if (n >= N_NODES) return;                 // N_NODES even -> n+1 also valid
    float d0 = 1.0f, d1 = 1.0f;               // self-loop
#pragma unroll
    for (int c = 0; c < DC; ++c) {
        d0 += degp[c * N_NODES + n];
        d1 += degp[c * N_NODES + n + 1];
    }
    float dv0 = rsqrtf(d0), dv1 = rsqrtf(d1);
    dinv[n] = dv0; dinv[n + 1] = dv1;
    const float4* xp = (const float4*)(x + (size_t)n * 6);
    float4 xa = xp[0], xb = xp[1], xc = xp[2];
    float4* op = (float4*)(xs_pad + (size_t)n * 8);
    op[0] = make_float4(xa.x * dv0, xa.y * dv0, xa.z * dv0, xa.w * dv0);
    op[1] = make_float4(xb.x * dv0, xb.y * dv0, 0.0f, 0.0f);
    op[2] = make_float4(xb.z * dv1, xb.w * dv1, xc.x * dv1, xc.y * dv1);
    op[3] = make_float4(xc.z * dv1, xc.w * dv1, 0.0f, 0.0f);
    mark_gstart(batch, n, gstart);
    mark_gstart(batch, n + 1, gstart);
}

// feature scatter over segmented bucket: block (w,c) scans segments
// b ≡ c (mod CB), count-masked, batched gathers before LDS atomics, flushes
// partial. [scan structure from proven round-6 k_feat]
__global__ __launch_bounds__(512) void k_feat(const int* __restrict__ bucket,
                                              const int* __restrict__ counts,
                                              const float* __restrict__ xs_pad,
                                              float* __restrict__ s_part) {
    __shared__ float h[NWF * 6];
    __shared__ int scnt[32];
    int w = blockIdx.x, c = blockIdx.y;
    int t = threadIdx.x;
    float4* h4 = (float4*)h;
    for (int i = t; i < NWF * 6 / 4; i += 512) h4[i] = make_float4(0, 0, 0, 0);
    int nseg = (PB - 1 - c) / CB + 1;
    if (t < nseg) scnt[t] = counts[w * PB + c + CB * t];
    __syncthreads();
    int total = nseg * SEGCAP;
    int base = (w * PB + c) * SEGCAP;
    int s = t;
    for (; s + 3 * 512 < total; s += 4 * 512) {
        int s0 = s, s1 = s + 512, s2 = s + 1024, s3 = s + 1536;
        int j0 = s0 / SEGCAP, j1 = s1 / SEGCAP, j2 = s2 / SEGCAP, j3 = s3 / SEGCAP;
        int e0 = s0 - j0 * SEGCAP, e1 = s1 - j1 * SEGCAP, e2 = s2 - j2 * SEGCAP, e3 = s3 - j3 * SEGCAP;
        bool v0 = e0 < scnt[j0], v1 = e1 < scnt[j1], v2 = e2 < scnt[j2], v3 = e3 < scnt[j3];
        int p0 = 0, p1 = 0, p2 = 0, p3 = 0;
        if (v0) p0 = bucket[base + j0 * (CB * SEGCAP) + e0];
        if (v1) p1 = bucket[base + j1 * (CB * SEGCAP) + e1];
        if (v2) p2 = bucket[base + j2 * (CB * SEGCAP) + e2];
        if (v3) p3 = bucket[base + j3 * (CB * SEGCAP) + e3];
        float4 a0, b0, a1, b1, a2, b2, a3, b3;
        if (v0) { const float4* q = (const float4*)(xs_pad + (size_t)(p0 & 0xffff) * 8); a0 = q[0]; b0 = q[1]; }
        if (v1) { const float4* q = (const float4*)(xs_pad + (size_t)(p1 & 0xffff) * 8); a1 = q[0]; b1 = q[1]; }
        if (v2) { const float4* q = (const float4*)(xs_pad + (size_t)(p2 & 0xffff) * 8); a2 = q[0]; b2 = q[1]; }
        if (v3) { const float4* q = (const float4*)(xs_pad + (size_t)(p3 & 0xffff) * 8); a3 = q[0]; b3 = q[1]; }
        float* hp;
        if (v0) {
            hp = &h[(((unsigned)p0) >> 16) * 6];
            atomicAdd(hp + 0, a0.x); atomicAdd(hp + 1, a0.y); atomicAdd(hp + 2, a0.z);
            atomicAdd(hp + 3, a0.w); atomicAdd(hp + 4, b0.x); atomicAdd(hp + 5, b0.y);
        }
        if (v1) {
            hp = &h[(((unsigned)p1) >> 16) * 6];
            atomicAdd(hp + 0, a1.x); atomicAdd(hp + 1, a1.y); atomicAdd(hp + 2, a1.z);
            atomicAdd(hp + 3, a1.w); atomicAdd(hp + 4, b1.x); atomicAdd(hp + 5, b1.y);
        }
        if (v2) {
            hp = &h[(((unsigned)p2) >> 16) * 6];
            atomicAdd(hp + 0, a2.x); atomicAdd(hp + 1, a2.y); atomicAdd(hp + 2, a2.z);
            atomicAdd(hp + 3, a2.w); atomicAdd(hp + 4, b2.x); atomicAdd(hp + 5, b2.y);
        }
        if (v3) {
            hp = &h[(((unsigned)p3) >> 16) * 6];
            atomicAdd(hp + 0, a3.x); atomicAdd(hp + 1, a3.y); atomicAdd(hp + 2, a3.z);
            atomicAdd(hp + 3, a3.w); atomicAdd(hp + 4, b3.x); atomicAdd(hp + 5, b3.y);
        }
    }
    for (; s < total; s += 512) {
        int j = s / SEGCAP, e = s - j * SEGCAP;
        if (e < scnt[j]) {
            int p = bucket[base + j * (CB * SEGCAP) + e];
            const float4* q = (const float4*)(xs_pad + (size_t)(p & 0xffff) * 8);
            float4 a = q[0], bq = q[1];
            float* hp = &h[(((unsigned)p) >> 16) * 6];
            atomicAdd(hp + 0, a.x); atomicAdd(hp + 1, a.y); atomicAdd(hp + 2, a.z);
            atomicAdd(hp + 3, a.w); atomicAdd(hp + 4, bq.x); atomicAdd(hp + 5, bq.y);
        }
    }
    __syncthreads();
    int gb = w * NWF * 6;
    int lim = min(NWF * 6, N6 - gb);      // multiple of 4
    float4* sp4 = (float4*)(s_part + (size_t)c * N6 + gb);
    for (int i = t; i < lim / 4; i += 512) sp4[i] = h4[i];
}

// fused node+head: block owns 4 whole graphs (no atomics, fixed order ->
// deterministic). [proven round 13]
__global__ __launch_bounds__(512) void k_nodehead(const float* __restrict__ s_part,
                                                  const float* __restrict__ xs_pad,
                                                  const float* __restrict__ dinv,
                                                  const int* __restrict__ gstart,
                                                  const float* __restrict__ w1,
                                                  const float* __restrict__ b1,
                                                  const float* __restrict__ wl,
                                                  const float* __restrict__ bl,
                                                  const float* __restrict__ w2,
                                                  const float* __restrict__ b2,
                                                  float* __restrict__ out) {
    __shared__ float sb[MAXN * 6];
    __shared__ float dvb[MAXN];
    __shared__ float sg[4 * HID];
    __shared__ float sg2[4 * HID];
    __shared__ int gb[5];
    int t = threadIdx.x;
    int g0 = blockIdx.x * 4;
    if (t < 5) gb[t] = gstart[g0 + t];
    __syncthreads();
    int ns = gb[0], ne = gb[4];
    int sub = t >> 7, f = t & (HID - 1);
    float w1r[6];
#pragma unroll
    for (int k = 0; k < 6; ++k) w1r[k] = w1[k * HID + f];
    float b1f = b1[f];
    float acc = 0.0f;

    for (int base = ns; base < ne; base += MAXN) {
        int cc = min(MAXN, ne - base);
        __syncthreads();                       // protect sb/dvb reuse across chunks
        {
            float2* sb2 = (float2*)sb;
            int nel = cc * 3;
            int g2 = base * 3;
            for (int i = t; i < nel; i += 512) {
                float2 v = make_float2(0.0f, 0.0f);
#pragma unroll
                for (int c = 0; c < CB; ++c) {
                    float2 p = ((const float2*)(s_part + (size_t)c * N6))[g2 + i];
                    v.x += p.x; v.y += p.y;
                }
                sb2[i] = v;
            }
        }
        for (int i = t; i < cc; i += 512) {
            int n = base + i;
            const float4* xp = (const float4*)(xs_pad + (size_t)n * 8);
            float4 a = xp[0], bq = xp[1];
            float* sp = &sb[i * 6];
            sp[0] += a.x; sp[1] += a.y; sp[2] += a.z;
            sp[3] += a.w; sp[4] += bq.x; sp[5] += bq.y;
            dvb[i] = dinv[n];
        }
        __syncthreads();
        int lo = max(gb[sub], base);
        int hi = min(gb[sub + 1], base + cc);
        for (int n = lo; n < hi; ++n) {
            int i = n - base;
            const float* sp = &sb[i * 6];
            float tv = 0.0f;
#pragma unroll
            for (int k = 0; k < 6; ++k) tv = fmaf(sp[k], w1r[k], tv);
            acc += fmaxf(fmaf(dvb[i], tv, b1f), 0.0f);
        }
    }

    int cnt = gb[sub + 1] - gb[sub];
    float ic = 1.0f / fmaxf((float)cnt, 1.0f);
    sg[sub * HID + f] = acc * ic;
    __syncthreads();

    float a2 = bl[f];
    for (int k = 0; k < HID; ++k) a2 = fmaf(sg[sub * HID + k], wl[k * HID + f], a2);
    sg2[sub * HID + f] = fmaxf(a2, 0.0f);
    __syncthreads();

    if (f < N_ACT) {
        float l = b2[f];
        for (int ff = 0; ff < HID; ++ff) l = fmaf(sg2[sub * HID + ff], w2[ff * N_ACT + f], l);
        float m = l;
#pragma unroll
        for (int off = 32; off > 0; off >>= 1) m = fmaxf(m, __shfl_xor(m, off));
        float e = expf(l - m);
        float ssum = e;
#pragma unroll
        for (int off = 32; off > 0; off >>= 1) ssum += __shfl_xor(ssum, off);
        out[(g0 + sub) * N_ACT + f] = l - m - logf(ssum);
    }
}

// ===================== fallback path (round-1, known-correct) =====================

__global__ void k_init(float* __restrict__ deg, float* __restrict__ gsum,
                       float* __restrict__ cnt) {
    int i = blockIdx.x * blockDim.x + threadIdx.x;
    if (i < N_NODES) deg[i] = 1.0f;
    if (i < N_GRAPH * HID) gsum[i] = 0.0f;
    if (i < N_GRAPH) cnt[i] = 0.0f;
}

__global__ void k_deg(const int* __restrict__ ei, float* __restrict__ deg) {
    int e = blockIdx.x * blockDim.x + threadIdx.x;
    if (e < N_EDGES) atomicAdd(&deg[ei[N_EDGES + e]], 1.0f);
}

__global__ void k_scale(const float* __restrict__ x, const int* __restrict__ batch,
                        const float* __restrict__ deg, float* __restrict__ dinv,
                        float* __restrict__ xs, float* __restrict__ s,
                        float* __restrict__ cnt) {
    int n = blockIdx.x * blockDim.x + threadIdx.x;
    if (n >= N_NODES) return;
    float dv = rsqrtf(deg[n]);
    dinv[n] = dv;
#pragma unroll
    for (int k = 0; k < 6; ++k) {
        float v = x[n * 6 + k] * dv;
        xs[n * 6 + k] = v;
        s[n * 6 + k] = v;
    }
    atomicAdd(&cnt[batch[n]], 1.0f);
}

__global__ void k_scatter(const int* __restrict__ ei, const float* __restrict__ xs,
                          float* __restrict__ s) {
    int e = blockIdx.x * blockDim.x + threadIdx.x;
    if (e >= N_EDGES) return;
    int src = ei[e];
    int dst = ei[N_EDGES + e];
#pragma unroll
    for (int k = 0; k < 6; ++k)
        atomicAdd(&s[dst * 6 + k], xs[src * 6 + k]);
}

__global__ __launch_bounds__(256) void k_node(const float* __restrict__ s,
                                              const float* __restrict__ dinv,
                                              const int* __restrict__ batch,
                                              const float* __restrict__ w1,
                                              const float* __restrict__ b1,
                                              float* __restrict__ gsum) {
    int f = threadIdx.x & (HID - 1);
    int sub = threadIdx.x >> 7;
    int base = blockIdx.x * 16 + sub * 8;
    float w1r[6];
#pragma unroll
    for (int k = 0; k < 6; ++k) w1r[k] = w1[k * HID + f];
    float b1f = b1[f];
    float acc = 0.0f;
    int curb = -1;
    for (int i = 0; i < 8; ++i) {
        int n = base + i;
        if (n >= N_NODES) break;
        float t = 0.0f;
#pragma unroll
        for (int k = 0; k < 6; ++k) t = fmaf(s[n * 6 + k], w1r[k], t);
        float a = fmaxf(fmaf(dinv[n], t, b1f), 0.0f);
        int b = batch[n];
        if (b != curb) {
            if (curb >= 0) atomicAdd(&gsum[curb * HID + f], acc);
            acc = 0.0f;
            curb = b;
        }
        acc += a;
    }
    if (curb >= 0) atomicAdd(&gsum[curb * HID + f], acc);
}

__global__ __launch_bounds__(128) void k_head(const float* __restrict__ gsum,
                                              const float* __restrict__ cnt,
                                              const float* __restrict__ wl,
                                              const float* __restrict__ bl,
                                              const float* __restrict__ w2,
                                              const float* __restrict__ b2,
                                              float* __restrict__ out) {
    __shared__ float sg[HID];
    __shared__ float sg2[HID];
    int g = blockIdx.x;
    int t = threadIdx.x;

    float ic = 1.0f / fmaxf(cnt[g], 1.0f);
    sg[t] = gsum[g * HID + t] * ic;
    __syncthreads();

    float acc = bl[t];
    for (int k = 0; k < HID; ++k) acc = fmaf(sg[k], wl[k * HID + t], acc);
    sg2[t] = fmaxf(acc, 0.0f);
    __syncthreads();

    if (t < N_ACT) {
        float l = b2[t];
        for (int f = 0; f < HID; ++f) l = fmaf(sg2[f], w2[f * N_ACT + t], l);
        float m = l;
#pragma unroll
        for (int off = 32; off > 0; off >>= 1) m = fmaxf(m, __shfl_xor(m, off));
        float e = expf(l - m);
        float ssum = e;
#pragma unroll
        for (int off = 32; off > 0; off >>= 1) ssum += __shfl_xor(ssum, off);
        out[g * N_ACT + t] = l - m - logf(ssum);
    }
}

// ===================== launch =====================

extern "C" void kernel_launch(void* const* d_in, const int* in_sizes, int n_in,
                              void* d_out, int out_size, void* d_ws, size_t ws_size,
                              hipStream_t stream) {
    const float* x     = (const float*)d_in[0];
    const int*   ei    = (const int*)d_in[1];
    const int*   batch = (const int*)d_in[2];
    const float* w1    = (const float*)d_in[3];
    const float* b1    = (const float*)d_in[4];
    const float* wl    = (const float*)d_in[5];
    const float* bl    = (const float*)d_in[6];
    const float* w2    = (const float*)d_in[7];
    const float* b2    = (const float*)d_in[8];
    float* out = (float*)d_out;
    float* ws = (float*)d_ws;

    if (ws_size >= NEED_BYTES) {
        int*   bucket = (int*)(ws + F_BUCKET);
        int*   counts = (int*)(ws + F_COUNTS);
        int*   gstart = (int*)(ws + F_GSTART);
        float* dinv   = ws + F_DINV;
        float* xs_pad = ws + F_XSPAD;
        float* degp   = ws + F_DEGP;
        float* s_part = ws + F_SPART;

        k_place<<<PB, 512, 0, stream>>>(ei, bucket, counts);
        k_degp<<<dim3(WF, DC), 512, 0, stream>>>(bucket, counts, degp);
        k_scale2<<<(N_NODES + 511) / 512, 256, 0, stream>>>(degp, x, batch, dinv, xs_pad, gstart);
        k_feat<<<dim3(WF, CB), 512, 0, stream>>>(bucket, counts, xs_pad, s_part);
        k_nodehead<<<N_GRAPH / 4, 512, 0, stream>>>(s_part, xs_pad, dinv, gstart,
                                                    w1, b1, wl, bl, w2, b2, out);
    } else {
        float* deg  = ws;
        float* dinv = deg + N_NODES;
        float* xs   = dinv + N_NODES;
        float* s    = xs + N6;
        float* gsum = s + N6;
        float* cnt  = gsum + N_GRAPH * HID;

        k_init<<<(N_GRAPH * HID + 255) / 256, 256, 0, stream>>>(deg, gsum, cnt);
        k_deg<<<(N_EDGES + 255) / 256, 256, 0, stream>>>(ei, deg);
        k_scale<<<(N_NODES + 255) / 256, 256, 0, stream>>>(x, batch, deg, dinv, xs, s, cnt);
        k_scatter<<<(N_EDGES + 255) / 256, 256, 0, stream>>>(ei, xs, s);
        k_node<<<(N_NODES + 15) / 16, 256, 0, stream>>>(s, dinv, batch, w1, b1, gsum);
        k_head<<<N_GRAPH, 128, 0, stream>>>(gsum, cnt, wl, bl, w2, b2, out);
    }
}